// Round 7
// baseline (472.471 us; speedup 1.0000x reference)
//
#include <hip/hip_runtime.h>

#define DIM 256

// ---------------------------------------------------------------------------
// GEMM: hidden[i][j] = sum_k x2[i][k] * W[j][k] + b[j]
// fp32 -> vector ALU (no fp32 MFMA on CDNA4). LDS-tiled 64x64x32, 256 thr.
// M-major LDS tiles padded to stride 36 (16B aligned). Strided microtile
// (rows ty+16i, cols tx+16j) so per-thread K-reads are ds_read_b128.
// Read bank pattern: A = 4-addr broadcast (conflict-free), B = 2-way (free).
// ---------------------------------------------------------------------------
#define BM 64
#define BN 64
#define BK 32
#define LDP 36   // padded K-stride (floats): %4==0 keeps b128 alignment

__global__ __launch_bounds__(256) void gemm_xwT(
    const float* __restrict__ x2, const float* __restrict__ W,
    const float* __restrict__ bias, float* __restrict__ hidden, int n)
{
    __shared__ float As[BM][LDP];
    __shared__ float Bs[BN][LDP];

    const int tid = threadIdx.x;
    const int tx = tid & 15;   // col group: cols tx + 16j
    const int ty = tid >> 4;   // row group: rows ty + 16i
    const int i0 = blockIdx.x * BM;
    const int j0 = blockIdx.y * BN;

    float acc[4][4] = {};

    for (int k0 = 0; k0 < DIM; k0 += BK) {
        #pragma unroll
        for (int s = 0; s < 2; ++s) {
            const int slot = tid + s * 256;
            const int row  = slot >> 3;         // 0..63
            const int k4   = (slot & 7) << 2;   // 0,4,...,28
            const int gi = i0 + row;
            float4 va = make_float4(0.f, 0.f, 0.f, 0.f);
            if (gi < n)
                va = *reinterpret_cast<const float4*>(x2 + (size_t)gi * DIM + k0 + k4);
            *reinterpret_cast<float4*>(&As[row][k4]) = va;
            const float4 vb = *reinterpret_cast<const float4*>(
                W + (size_t)(j0 + row) * DIM + k0 + k4);
            *reinterpret_cast<float4*>(&Bs[row][k4]) = vb;
        }
        __syncthreads();

        #pragma unroll
        for (int kk = 0; kk < BK; kk += 4) {
            float4 a[4], b[4];
            #pragma unroll
            for (int i = 0; i < 4; ++i)
                a[i] = *reinterpret_cast<const float4*>(&As[ty + 16 * i][kk]);
            #pragma unroll
            for (int j = 0; j < 4; ++j)
                b[j] = *reinterpret_cast<const float4*>(&Bs[tx + 16 * j][kk]);
            #pragma unroll
            for (int i = 0; i < 4; ++i)
                #pragma unroll
                for (int j = 0; j < 4; ++j) {
                    acc[i][j] += a[i].x * b[j].x;
                    acc[i][j] += a[i].y * b[j].y;
                    acc[i][j] += a[i].z * b[j].z;
                    acc[i][j] += a[i].w * b[j].w;
                }
        }
        __syncthreads();
    }

    float bv[4];
    #pragma unroll
    for (int j = 0; j < 4; ++j) bv[j] = bias[j0 + tx + 16 * j];

    #pragma unroll
    for (int i = 0; i < 4; ++i) {
        const int gi = i0 + ty + 16 * i;
        if (gi < n) {
            #pragma unroll
            for (int j = 0; j < 4; ++j)
                hidden[(size_t)gi * DIM + j0 + tx + 16 * j] = acc[i][j] + bv[j];
        }
    }
}

// ---------------------------------------------------------------------------
// CSR build: histogram -> exclusive scan (2-level) -> bucket fill
// ---------------------------------------------------------------------------
__global__ __launch_bounds__(256) void histo(
    const int* __restrict__ rows, int* __restrict__ deg, int n_edges)
{
    int e = blockIdx.x * 256 + threadIdx.x;
    const int stride = gridDim.x * 256;
    for (; e < n_edges; e += stride)
        atomicAdd(&deg[rows[e]], 1);
}

__global__ __launch_bounds__(256) void scan_block(
    const int* __restrict__ deg, int* __restrict__ offs,
    int* __restrict__ bsums, int n)
{
    __shared__ int s[256];
    const int gid = blockIdx.x * 256 + threadIdx.x;
    const int v = (gid < n) ? deg[gid] : 0;
    s[threadIdx.x] = v;
    __syncthreads();
    #pragma unroll
    for (int d = 1; d < 256; d <<= 1) {
        const int t = (threadIdx.x >= d) ? s[threadIdx.x - d] : 0;
        __syncthreads();
        s[threadIdx.x] += t;
        __syncthreads();
    }
    if (gid < n) offs[gid] = s[threadIdx.x] - v;     // exclusive within block
    if (threadIdx.x == 255) bsums[blockIdx.x] = s[255];
}

__global__ __launch_bounds__(256) void scan_sums(int* __restrict__ bsums, int nb)
{
    __shared__ int s[256];
    const int v = (threadIdx.x < nb) ? bsums[threadIdx.x] : 0;
    s[threadIdx.x] = v;
    __syncthreads();
    #pragma unroll
    for (int d = 1; d < 256; d <<= 1) {
        const int t = (threadIdx.x >= d) ? s[threadIdx.x - d] : 0;
        __syncthreads();
        s[threadIdx.x] += t;
        __syncthreads();
    }
    if (threadIdx.x < nb) bsums[threadIdx.x] = s[threadIdx.x] - v;  // exclusive
}

__global__ __launch_bounds__(256) void scan_add(
    int* __restrict__ offs, const int* __restrict__ bsums, int n, int n_edges)
{
    const int gid = blockIdx.x * 256 + threadIdx.x;
    if (gid < n) offs[gid] += bsums[blockIdx.x];
    if (gid == n - 1) offs[n] = n_edges;
}

// pos = offs[r] + (deg[r]-- - 1); deg is consumed down to zero.
// Packs (col, val) into int2 for a single 8B broadcast load per edge later.
__global__ __launch_bounds__(256) void bucket_fill(
    const int* __restrict__ rows, const int* __restrict__ cols,
    const float* __restrict__ vals, const int* __restrict__ offs,
    int* __restrict__ deg, int2* __restrict__ eb, int n_edges)
{
    int e = blockIdx.x * 256 + threadIdx.x;
    const int stride = gridDim.x * 256;
    for (; e < n_edges; e += stride) {
        const int r = rows[e];
        const int old = atomicSub(&deg[r], 1);
        const int pos = offs[r] + old - 1;
        eb[pos] = make_int2(cols[e], __float_as_int(vals[e]));
    }
}

// ---------------------------------------------------------------------------
// Aggregation (gather, no atomics) + fused epilogue.
// One 64-lane wave per node; lane holds float4 (4 of 256 features).
// Unrolled x4, two independent accumulator chains -> 4 gathers in flight,
// halved FMA dependency stalls.
// y1 = relu(sum_e val*hidden[col]) + x1 ; y2 = x2.
// ---------------------------------------------------------------------------
__global__ __launch_bounds__(256) void aggregate(
    const float* __restrict__ hidden, const int* __restrict__ offs,
    const int2* __restrict__ eb,
    const float* __restrict__ x1, const float* __restrict__ x2,
    float* __restrict__ y2, float* __restrict__ y1, int n)
{
    const int lane = threadIdx.x & 63;
    const int node = blockIdx.x * 4 + (threadIdx.x >> 6);
    if (node >= n) return;

    const int s = offs[node];
    const int e = offs[node + 1];
    const size_t fofs = (size_t)(lane * 4);

    float4 acc0 = make_float4(0.f, 0.f, 0.f, 0.f);
    float4 acc1 = make_float4(0.f, 0.f, 0.f, 0.f);

    int i = s;
    for (; i + 3 < e; i += 4) {
        const int2 p0 = eb[i + 0];
        const int2 p1 = eb[i + 1];
        const int2 p2 = eb[i + 2];
        const int2 p3 = eb[i + 3];
        const float4 h0 = *reinterpret_cast<const float4*>(
            hidden + (size_t)p0.x * DIM + fofs);
        const float4 h1 = *reinterpret_cast<const float4*>(
            hidden + (size_t)p1.x * DIM + fofs);
        const float4 h2 = *reinterpret_cast<const float4*>(
            hidden + (size_t)p2.x * DIM + fofs);
        const float4 h3 = *reinterpret_cast<const float4*>(
            hidden + (size_t)p3.x * DIM + fofs);
        const float v0 = __int_as_float(p0.y);
        const float v1 = __int_as_float(p1.y);
        const float v2 = __int_as_float(p2.y);
        const float v3 = __int_as_float(p3.y);
        acc0.x += v0 * h0.x + v1 * h1.x;
        acc0.y += v0 * h0.y + v1 * h1.y;
        acc0.z += v0 * h0.z + v1 * h1.z;
        acc0.w += v0 * h0.w + v1 * h1.w;
        acc1.x += v2 * h2.x + v3 * h3.x;
        acc1.y += v2 * h2.y + v3 * h3.y;
        acc1.z += v2 * h2.z + v3 * h3.z;
        acc1.w += v2 * h2.w + v3 * h3.w;
    }
    for (; i < e; ++i) {
        const int2 p0 = eb[i];
        const float v0 = __int_as_float(p0.y);
        const float4 h0 = *reinterpret_cast<const float4*>(
            hidden + (size_t)p0.x * DIM + fofs);
        acc0.x += v0 * h0.x;
        acc0.y += v0 * h0.y;
        acc0.z += v0 * h0.z;
        acc0.w += v0 * h0.w;
    }
    acc0.x += acc1.x; acc0.y += acc1.y; acc0.z += acc1.z; acc0.w += acc1.w;

    const size_t base = (size_t)node * DIM + fofs;
    const float4 a  = *reinterpret_cast<const float4*>(x1 + base);
    const float4 xx = *reinterpret_cast<const float4*>(x2 + base);
    float4 o;
    o.x = fmaxf(acc0.x, 0.f) + a.x;
    o.y = fmaxf(acc0.y, 0.f) + a.y;
    o.z = fmaxf(acc0.z, 0.f) + a.z;
    o.w = fmaxf(acc0.w, 0.f) + a.w;
    *reinterpret_cast<float4*>(y1 + base) = o;
    *reinterpret_cast<float4*>(y2 + base) = xx;
}

// ---------------------------------------------------------------------------
// Fallback path (atomic scatter) if ws_size is too small for CSR build.
// ---------------------------------------------------------------------------
__global__ __launch_bounds__(256) void edge_scatter(
    const float* __restrict__ hidden,
    const int* __restrict__ rows, const int* __restrict__ cols,
    const float* __restrict__ vals,
    float* __restrict__ support, int n_edges)
{
    const int lane = threadIdx.x & 63;
    const int wslot = (blockIdx.x << 2) | (threadIdx.x >> 6);
    const int n_slots = gridDim.x << 2;
    for (int e = wslot; e < n_edges; e += n_slots) {
        const int r = rows[e];
        const int c = cols[e];
        const float v = vals[e];
        const float4 h = *reinterpret_cast<const float4*>(
            hidden + (size_t)c * DIM + lane * 4);
        float* sp = support + (size_t)r * DIM + lane * 4;
        atomicAdd(sp + 0, v * h.x);
        atomicAdd(sp + 1, v * h.y);
        atomicAdd(sp + 2, v * h.z);
        atomicAdd(sp + 3, v * h.w);
    }
}

__global__ __launch_bounds__(256) void epilogue(
    const float* __restrict__ x1, const float* __restrict__ x2,
    float* __restrict__ out_y2, float* __restrict__ out_y1, size_t total4)
{
    const float4* x1v = reinterpret_cast<const float4*>(x1);
    const float4* x2v = reinterpret_cast<const float4*>(x2);
    float4* y2v = reinterpret_cast<float4*>(out_y2);
    float4* y1v = reinterpret_cast<float4*>(out_y1);
    size_t i = (size_t)blockIdx.x * blockDim.x + threadIdx.x;
    const size_t stride = (size_t)gridDim.x * blockDim.x;
    for (; i < total4; i += stride) {
        y2v[i] = x2v[i];
        float4 s = y1v[i];
        float4 a = x1v[i];
        float4 o;
        o.x = fmaxf(s.x, 0.f) + a.x;
        o.y = fmaxf(s.y, 0.f) + a.y;
        o.z = fmaxf(s.z, 0.f) + a.z;
        o.w = fmaxf(s.w, 0.f) + a.w;
        y1v[i] = o;
    }
}

extern "C" void kernel_launch(void* const* d_in, const int* in_sizes, int n_in,
                              void* d_out, int out_size, void* d_ws, size_t ws_size,
                              hipStream_t stream) {
    const float* x1   = (const float*)d_in[0];
    const float* x2   = (const float*)d_in[1];
    const int*   rows = (const int*)d_in[2];
    const int*   cols = (const int*)d_in[3];
    const float* vals = (const float*)d_in[4];
    const float* W    = (const float*)d_in[5];
    const float* bias = (const float*)d_in[6];

    const int n_nodes = in_sizes[0] / DIM;
    const int n_edges = in_sizes[2];
    const int nb = (n_nodes + 255) / 256;   // scan blocks (<=256 required)

    float* out     = (float*)d_out;
    float* out_y2  = out;                              // y2 = x2
    float* out_y1  = out + (size_t)n_nodes * DIM;      // y1

    // workspace layout
    char* ws = (char*)d_ws;
    float* hidden = (float*)ws;                         // N*D floats
    size_t off = (size_t)n_nodes * DIM * sizeof(float);
    int* offs  = (int*)(ws + off);  off += (size_t)(n_nodes + 1) * sizeof(int);
    int* deg   = (int*)(ws + off);  off += (size_t)n_nodes * sizeof(int);
    int* bsums = (int*)(ws + off);  off += 256 * sizeof(int);
    off = (off + 15) & ~(size_t)15;
    int2* eb   = (int2*)(ws + off); off += (size_t)n_edges * sizeof(int2);
    const bool csr_ok = (off <= ws_size) && (nb <= 256);

    // 1) hidden = x2 @ W^T + b
    dim3 ggrid((n_nodes + BM - 1) / BM, DIM / BN);
    gemm_xwT<<<ggrid, 256, 0, stream>>>(x2, W, bias, hidden, n_nodes);

    if (csr_ok) {
        // 2) CSR build
        (void)hipMemsetAsync(deg, 0, (size_t)n_nodes * sizeof(int), stream);
        histo<<<(n_edges + 255) / 256, 256, 0, stream>>>(rows, deg, n_edges);
        scan_block<<<nb, 256, 0, stream>>>(deg, offs, bsums, n_nodes);
        scan_sums<<<1, 256, 0, stream>>>(bsums, nb);
        scan_add<<<nb, 256, 0, stream>>>(offs, bsums, n_nodes, n_edges);
        bucket_fill<<<(n_edges + 255) / 256, 256, 0, stream>>>(
            rows, cols, vals, offs, deg, eb, n_edges);

        // 3) gather-aggregate + fused epilogue
        aggregate<<<(n_nodes + 3) / 4, 256, 0, stream>>>(
            hidden, offs, eb, x1, x2, out_y2, out_y1, n_nodes);
    } else {
        // fallback: atomic scatter into out_y1 (used as support accumulator)
        (void)hipMemsetAsync(out_y1, 0, (size_t)n_nodes * DIM * sizeof(float), stream);
        edge_scatter<<<2048, 256, 0, stream>>>(hidden, rows, cols, vals,
                                               out_y1, n_edges);
        const size_t total4 = (size_t)n_nodes * DIM / 4;
        epilogue<<<2048, 256, 0, stream>>>(x1, x2, out_y2, out_y1, total4);
    }
}

// Round 9
// 423.357 us; speedup vs baseline: 1.1160x; 1.1160x over previous
//
#include <hip/hip_runtime.h>
#include <hip/hip_fp16.h>

#define DIM 256

typedef float  f32x4 __attribute__((ext_vector_type(4)));
typedef int    i32x2 __attribute__((ext_vector_type(2)));
typedef _Float16 h16x8 __attribute__((ext_vector_type(8)));
typedef _Float16 h16x4 __attribute__((ext_vector_type(4)));

// Load 4 consecutive fp16 (8B) and upconvert.
__device__ inline float4 ld_h4(const _Float16* p) {
    const h16x4 h = *reinterpret_cast<const h16x4*>(p);
    return make_float4((float)h[0], (float)h[1], (float)h[2], (float)h[3]);
}

// ---------------------------------------------------------------------------
// W (fp32 [256][256]) -> Wh (fp16), one-shot.
// ---------------------------------------------------------------------------
__global__ __launch_bounds__(256) void cvt_w(
    const float* __restrict__ W, _Float16* __restrict__ Wh)
{
    const int i = blockIdx.x * 256 + threadIdx.x;   // grid = 256 blocks
    Wh[i] = (_Float16)W[i];
}

// ---------------------------------------------------------------------------
// MFMA GEMM: hidden[i][j] = sum_k x2[i][k] * W[j][k] + b[j], fp16 out.
// One wave per 16-row M-tile, covering all 256 output cols (16 col-tiles).
// A-frag: lane holds x2[m0 + (lane&15)][kb..kb+7] (fp32->fp16 inline).
// B-frag: lane holds W[jt*16 + (lane&15)][kb..kb+7] (= W^T[k][col]).
// Identical k-mapping on A and B => any hw k-permutation cancels.
// C/D: col = lane&15, row = (lane>>4)*4 + reg   [HW-verified mapping].
// ---------------------------------------------------------------------------
__global__ __launch_bounds__(256) void gemm_mfma(
    const float* __restrict__ x2, const _Float16* __restrict__ Wh,
    const float* __restrict__ bias, _Float16* __restrict__ hidden,
    int n, int n_tiles)
{
    const int wid  = threadIdx.x >> 6;
    const int lane = threadIdx.x & 63;
    const int tile = blockIdx.x * 4 + wid;
    if (tile >= n_tiles) return;

    const int r16  = lane & 15;   // M-row within tile / N-col within tile
    const int kgrp = lane >> 4;   // 0..3
    const int m0   = tile * 16;

    f32x4 acc[16];
    #pragma unroll
    for (int t = 0; t < 16; ++t) acc[t] = (f32x4){0.f, 0.f, 0.f, 0.f};

    const int arow = (m0 + r16 < n) ? (m0 + r16) : (n - 1);
    const float* ap = x2 + (size_t)arow * DIM;

    #pragma unroll
    for (int ks = 0; ks < 8; ++ks) {
        const int kb = ks * 32 + kgrp * 8;
        const float4 a01 = *reinterpret_cast<const float4*>(ap + kb);
        const float4 a23 = *reinterpret_cast<const float4*>(ap + kb + 4);
        h16x8 af;
        af[0] = (_Float16)a01.x; af[1] = (_Float16)a01.y;
        af[2] = (_Float16)a01.z; af[3] = (_Float16)a01.w;
        af[4] = (_Float16)a23.x; af[5] = (_Float16)a23.y;
        af[6] = (_Float16)a23.z; af[7] = (_Float16)a23.w;
        #pragma unroll
        for (int jt = 0; jt < 16; ++jt) {
            const h16x8 bf = *reinterpret_cast<const h16x8*>(
                Wh + (size_t)(jt * 16 + r16) * DIM + kb);
            acc[jt] = __builtin_amdgcn_mfma_f32_16x16x32_f16(af, bf, acc[jt], 0, 0, 0);
        }
    }

    #pragma unroll
    for (int jt = 0; jt < 16; ++jt) {
        const int col = jt * 16 + r16;
        const float bv = bias[col];
        #pragma unroll
        for (int r = 0; r < 4; ++r) {
            const int grow = m0 + kgrp * 4 + r;
            if (grow < n)
                hidden[(size_t)grow * DIM + col] = (_Float16)(acc[jt][r] + bv);
        }
    }
}

// ---------------------------------------------------------------------------
// CSR build: histogram -> exclusive scan (2-level) -> bucket fill
// ---------------------------------------------------------------------------
__global__ __launch_bounds__(256) void histo(
    const int* __restrict__ rows, int* __restrict__ deg, int n_edges)
{
    int e = blockIdx.x * 256 + threadIdx.x;
    const int stride = gridDim.x * 256;
    for (; e < n_edges; e += stride)
        atomicAdd(&deg[rows[e]], 1);
}

__global__ __launch_bounds__(256) void scan_block(
    const int* __restrict__ deg, int* __restrict__ offs,
    int* __restrict__ bsums, int n)
{
    __shared__ int s[256];
    const int gid = blockIdx.x * 256 + threadIdx.x;
    const int v = (gid < n) ? deg[gid] : 0;
    s[threadIdx.x] = v;
    __syncthreads();
    #pragma unroll
    for (int d = 1; d < 256; d <<= 1) {
        const int t = (threadIdx.x >= d) ? s[threadIdx.x - d] : 0;
        __syncthreads();
        s[threadIdx.x] += t;
        __syncthreads();
    }
    if (gid < n) offs[gid] = s[threadIdx.x] - v;     // exclusive within block
    if (threadIdx.x == 255) bsums[blockIdx.x] = s[255];
}

__global__ __launch_bounds__(256) void scan_sums(int* __restrict__ bsums, int nb)
{
    __shared__ int s[256];
    const int v = (threadIdx.x < nb) ? bsums[threadIdx.x] : 0;
    s[threadIdx.x] = v;
    __syncthreads();
    #pragma unroll
    for (int d = 1; d < 256; d <<= 1) {
        const int t = (threadIdx.x >= d) ? s[threadIdx.x - d] : 0;
        __syncthreads();
        s[threadIdx.x] += t;
        __syncthreads();
    }
    if (threadIdx.x < nb) bsums[threadIdx.x] = s[threadIdx.x] - v;  // exclusive
}

__global__ __launch_bounds__(256) void scan_add(
    int* __restrict__ offs, const int* __restrict__ bsums, int n, int n_edges)
{
    const int gid = blockIdx.x * 256 + threadIdx.x;
    if (gid < n) offs[gid] += bsums[blockIdx.x];
    if (gid == n - 1) offs[n] = n_edges;
}

__global__ __launch_bounds__(256) void bucket_fill(
    const int* __restrict__ rows, const int* __restrict__ cols,
    const float* __restrict__ vals, const int* __restrict__ offs,
    int* __restrict__ deg, int2* __restrict__ eb, int n_edges)
{
    int e = blockIdx.x * 256 + threadIdx.x;
    const int stride = gridDim.x * 256;
    for (; e < n_edges; e += stride) {
        const int r = rows[e];
        const int old = atomicSub(&deg[r], 1);
        const int pos = offs[r] + old - 1;
        eb[pos] = make_int2(cols[e], __float_as_int(vals[e]));
    }
}

// ---------------------------------------------------------------------------
// Aggregation (gather, no atomics) + fused epilogue.
// One 64-lane wave per node; lane holds 4 of 256 features (fp16 gather, 8B).
// Unrolled x4, two accumulator chains. Streaming traffic (eb, x1, x2, y1,
// y2) is non-temporal (ext_vector types) so L2/L3 retain hidden (reused).
// y1 = relu(sum_e val*hidden[col]) + x1 ; y2 = x2.
// ---------------------------------------------------------------------------
__global__ __launch_bounds__(256) void aggregate(
    const _Float16* __restrict__ hidden, const int* __restrict__ offs,
    const int2* __restrict__ eb,
    const float* __restrict__ x1, const float* __restrict__ x2,
    float* __restrict__ y2, float* __restrict__ y1, int n)
{
    const int lane = threadIdx.x & 63;
    const int node = blockIdx.x * 4 + (threadIdx.x >> 6);
    if (node >= n) return;

    const int s = offs[node];
    const int e = offs[node + 1];
    const size_t fofs = (size_t)(lane * 4);

    float4 acc0 = make_float4(0.f, 0.f, 0.f, 0.f);
    float4 acc1 = make_float4(0.f, 0.f, 0.f, 0.f);

    int i = s;
    for (; i + 3 < e; i += 4) {
        const i32x2 p0 = __builtin_nontemporal_load(
            reinterpret_cast<const i32x2*>(&eb[i + 0]));
        const i32x2 p1 = __builtin_nontemporal_load(
            reinterpret_cast<const i32x2*>(&eb[i + 1]));
        const i32x2 p2 = __builtin_nontemporal_load(
            reinterpret_cast<const i32x2*>(&eb[i + 2]));
        const i32x2 p3 = __builtin_nontemporal_load(
            reinterpret_cast<const i32x2*>(&eb[i + 3]));
        const float4 h0 = ld_h4(hidden + (size_t)p0[0] * DIM + fofs);
        const float4 h1 = ld_h4(hidden + (size_t)p1[0] * DIM + fofs);
        const float4 h2 = ld_h4(hidden + (size_t)p2[0] * DIM + fofs);
        const float4 h3 = ld_h4(hidden + (size_t)p3[0] * DIM + fofs);
        const float v0 = __int_as_float(p0[1]);
        const float v1 = __int_as_float(p1[1]);
        const float v2 = __int_as_float(p2[1]);
        const float v3 = __int_as_float(p3[1]);
        acc0.x += v0 * h0.x + v1 * h1.x;
        acc0.y += v0 * h0.y + v1 * h1.y;
        acc0.z += v0 * h0.z + v1 * h1.z;
        acc0.w += v0 * h0.w + v1 * h1.w;
        acc1.x += v2 * h2.x + v3 * h3.x;
        acc1.y += v2 * h2.y + v3 * h3.y;
        acc1.z += v2 * h2.z + v3 * h3.z;
        acc1.w += v2 * h2.w + v3 * h3.w;
    }
    for (; i < e; ++i) {
        const i32x2 p0 = __builtin_nontemporal_load(
            reinterpret_cast<const i32x2*>(&eb[i]));
        const float v0 = __int_as_float(p0[1]);
        const float4 h0 = ld_h4(hidden + (size_t)p0[0] * DIM + fofs);
        acc0.x += v0 * h0.x;
        acc0.y += v0 * h0.y;
        acc0.z += v0 * h0.z;
        acc0.w += v0 * h0.w;
    }
    acc0.x += acc1.x; acc0.y += acc1.y; acc0.z += acc1.z; acc0.w += acc1.w;

    const size_t base = (size_t)node * DIM + fofs;
    const f32x4 a  = __builtin_nontemporal_load(
        reinterpret_cast<const f32x4*>(x1 + base));
    const f32x4 xx = __builtin_nontemporal_load(
        reinterpret_cast<const f32x4*>(x2 + base));
    f32x4 o;
    o[0] = fmaxf(acc0.x, 0.f) + a[0];
    o[1] = fmaxf(acc0.y, 0.f) + a[1];
    o[2] = fmaxf(acc0.z, 0.f) + a[2];
    o[3] = fmaxf(acc0.w, 0.f) + a[3];
    __builtin_nontemporal_store(o,  reinterpret_cast<f32x4*>(y1 + base));
    __builtin_nontemporal_store(xx, reinterpret_cast<f32x4*>(y2 + base));
}

// ---------------------------------------------------------------------------
// Fallback path (atomic scatter) if ws_size is too small for CSR build.
// ---------------------------------------------------------------------------
__global__ __launch_bounds__(256) void edge_scatter(
    const _Float16* __restrict__ hidden,
    const int* __restrict__ rows, const int* __restrict__ cols,
    const float* __restrict__ vals,
    float* __restrict__ support, int n_edges)
{
    const int lane = threadIdx.x & 63;
    const int wslot = (blockIdx.x << 2) | (threadIdx.x >> 6);
    const int n_slots = gridDim.x << 2;
    for (int e = wslot; e < n_edges; e += n_slots) {
        const int r = rows[e];
        const int c = cols[e];
        const float v = vals[e];
        const float4 h = ld_h4(hidden + (size_t)c * DIM + lane * 4);
        float* sp = support + (size_t)r * DIM + lane * 4;
        atomicAdd(sp + 0, v * h.x);
        atomicAdd(sp + 1, v * h.y);
        atomicAdd(sp + 2, v * h.z);
        atomicAdd(sp + 3, v * h.w);
    }
}

__global__ __launch_bounds__(256) void epilogue(
    const float* __restrict__ x1, const float* __restrict__ x2,
    float* __restrict__ out_y2, float* __restrict__ out_y1, size_t total4)
{
    const float4* x1v = reinterpret_cast<const float4*>(x1);
    const float4* x2v = reinterpret_cast<const float4*>(x2);
    float4* y2v = reinterpret_cast<float4*>(out_y2);
    float4* y1v = reinterpret_cast<float4*>(out_y1);
    size_t i = (size_t)blockIdx.x * blockDim.x + threadIdx.x;
    const size_t stride = (size_t)gridDim.x * blockDim.x;
    for (; i < total4; i += stride) {
        y2v[i] = x2v[i];
        float4 s = y1v[i];
        float4 a = x1v[i];
        float4 o;
        o.x = fmaxf(s.x, 0.f) + a.x;
        o.y = fmaxf(s.y, 0.f) + a.y;
        o.z = fmaxf(s.z, 0.f) + a.z;
        o.w = fmaxf(s.w, 0.f) + a.w;
        y1v[i] = o;
    }
}

extern "C" void kernel_launch(void* const* d_in, const int* in_sizes, int n_in,
                              void* d_out, int out_size, void* d_ws, size_t ws_size,
                              hipStream_t stream) {
    const float* x1   = (const float*)d_in[0];
    const float* x2   = (const float*)d_in[1];
    const int*   rows = (const int*)d_in[2];
    const int*   cols = (const int*)d_in[3];
    const float* vals = (const float*)d_in[4];
    const float* W    = (const float*)d_in[5];
    const float* bias = (const float*)d_in[6];

    const int n_nodes = in_sizes[0] / DIM;
    const int n_edges = in_sizes[2];
    const int nb = (n_nodes + 255) / 256;   // scan blocks (<=256 required)

    float* out     = (float*)d_out;
    float* out_y2  = out;                              // y2 = x2
    float* out_y1  = out + (size_t)n_nodes * DIM;      // y1

    // workspace layout (hidden fp16, Wh fp16)
    char* ws = (char*)d_ws;
    _Float16* hidden = (_Float16*)ws;
    size_t off = (size_t)n_nodes * DIM * sizeof(_Float16);
    _Float16* Wh = (_Float16*)(ws + off); off += (size_t)DIM * DIM * sizeof(_Float16);
    int* offs  = (int*)(ws + off);  off += (size_t)(n_nodes + 1) * sizeof(int);
    int* deg   = (int*)(ws + off);  off += (size_t)n_nodes * sizeof(int);
    int* bsums = (int*)(ws + off);  off += 256 * sizeof(int);
    off = (off + 15) & ~(size_t)15;
    int2* eb   = (int2*)(ws + off); off += (size_t)n_edges * sizeof(int2);
    const bool csr_ok = (off <= ws_size) && (nb <= 256);

    // 1) Wh = fp16(W); hidden = x2 @ W^T + b  (MFMA fp16, fp32 accum)
    cvt_w<<<DIM * DIM / 256, 256, 0, stream>>>(W, Wh);
    const int n_tiles = (n_nodes + 15) / 16;
    gemm_mfma<<<(n_tiles + 3) / 4, 256, 0, stream>>>(
        x2, Wh, bias, hidden, n_nodes, n_tiles);

    if (csr_ok) {
        // 2) CSR build
        (void)hipMemsetAsync(deg, 0, (size_t)n_nodes * sizeof(int), stream);
        histo<<<(n_edges + 255) / 256, 256, 0, stream>>>(rows, deg, n_edges);
        scan_block<<<nb, 256, 0, stream>>>(deg, offs, bsums, n_nodes);
        scan_sums<<<1, 256, 0, stream>>>(bsums, nb);
        scan_add<<<nb, 256, 0, stream>>>(offs, bsums, n_nodes, n_edges);
        bucket_fill<<<(n_edges + 255) / 256, 256, 0, stream>>>(
            rows, cols, vals, offs, deg, eb, n_edges);

        // 3) gather-aggregate + fused epilogue
        aggregate<<<(n_nodes + 3) / 4, 256, 0, stream>>>(
            hidden, offs, eb, x1, x2, out_y2, out_y1, n_nodes);
    } else {
        // fallback: atomic scatter into out_y1 (used as support accumulator)
        (void)hipMemsetAsync(out_y1, 0, (size_t)n_nodes * DIM * sizeof(float), stream);
        edge_scatter<<<2048, 256, 0, stream>>>(hidden, rows, cols, vals,
                                               out_y1, n_edges);
        const size_t total4 = (size_t)n_nodes * DIM / 4;
        epilogue<<<2048, 256, 0, stream>>>(x1, x2, out_y2, out_y1, total4);
    }
}

// Round 10
// 368.888 us; speedup vs baseline: 1.2808x; 1.1477x over previous
//
#include <hip/hip_runtime.h>
#include <hip/hip_fp16.h>

#define DIM 256

typedef float  f32x4 __attribute__((ext_vector_type(4)));
typedef int    i32x2 __attribute__((ext_vector_type(2)));
typedef _Float16 h16x8 __attribute__((ext_vector_type(8)));
typedef _Float16 h16x4 __attribute__((ext_vector_type(4)));

// Load 4 consecutive fp16 (8B) and upconvert.
__device__ inline float4 ld_h4(const _Float16* p) {
    const h16x4 h = *reinterpret_cast<const h16x4*>(p);
    return make_float4((float)h[0], (float)h[1], (float)h[2], (float)h[3]);
}

// ---------------------------------------------------------------------------
// W (fp32 [256][256]) -> Wh (fp16), one-shot.
// ---------------------------------------------------------------------------
__global__ __launch_bounds__(256) void cvt_w(
    const float* __restrict__ W, _Float16* __restrict__ Wh)
{
    const int i = blockIdx.x * 256 + threadIdx.x;   // grid = 256 blocks
    Wh[i] = (_Float16)W[i];
}

// ---------------------------------------------------------------------------
// LDS-staged MFMA GEMM: hidden[i][j] = sum_k x2[i][k]*W[j][k] + b[j], fp16 out.
// 512 thr / 8 waves per block; wave w owns M-tile (blockIdx*8 + w) = 16 rows.
// A-frags (8 ks) preloaded to regs once, reused for both column halves.
// W fp16 staged in 64KB LDS per 128-col half, XOR-swizzled:
//   byte = j*512 + (ko ^ ((j&7)<<4))   [same involution on write and read]
// Fragment mapping identical to the HW-passed round-9 kernel:
//   A: lane holds x2[m0+(lane&15)][kb..kb+8), kb = ks*32+(lane>>4)*8
//   B: lane holds W [col       ][kb..kb+8), col = half*128+jt*16+(lane&15)
//   C: col = jt-block + (lane&15), row = m0 + (lane>>4)*4 + reg
// ---------------------------------------------------------------------------
__global__ __launch_bounds__(512) void gemm_mfma(
    const float* __restrict__ x2, const _Float16* __restrict__ Wh,
    const float* __restrict__ bias, _Float16* __restrict__ hidden,
    int n, int n_tiles)
{
    __shared__ _Float16 Bl[128 * DIM];   // 64 KB

    const int wid  = threadIdx.x >> 6;
    const int lane = threadIdx.x & 63;
    const int tile = blockIdx.x * 8 + wid;
    const bool act = (tile < n_tiles);

    const int r16  = lane & 15;
    const int kgrp = lane >> 4;
    const int m0   = tile * 16;

    // ---- A preload: 8 k-steps, fp32 -> fp16 in regs (32 VGPR) ----
    int arow = m0 + r16;
    if (!act || arow >= n) arow = 0;     // safe row; stores are guarded
    const float* ap = x2 + (size_t)arow * DIM;

    h16x8 af[8];
    #pragma unroll
    for (int ks = 0; ks < 8; ++ks) {
        const int kb = ks * 32 + kgrp * 8;
        const float4 a01 = *reinterpret_cast<const float4*>(ap + kb);
        const float4 a23 = *reinterpret_cast<const float4*>(ap + kb + 4);
        h16x8 v;
        v[0] = (_Float16)a01.x; v[1] = (_Float16)a01.y;
        v[2] = (_Float16)a01.z; v[3] = (_Float16)a01.w;
        v[4] = (_Float16)a23.x; v[5] = (_Float16)a23.y;
        v[6] = (_Float16)a23.z; v[7] = (_Float16)a23.w;
        af[ks] = v;
    }

    f32x4 acc[16];
    #pragma unroll
    for (int t = 0; t < 16; ++t) acc[t] = (f32x4){0.f, 0.f, 0.f, 0.f};

    char* blb = reinterpret_cast<char*>(Bl);

    #pragma unroll
    for (int half = 0; half < 2; ++half) {
        __syncthreads();   // half=1: wait until all waves done reading half 0
        // ---- stage 128 cols x 256 k of Wh into LDS (swizzled) ----
        // chunk c = s*512 + tid: per-instruction 512 consecutive 16B = coalesced
        const char* src = reinterpret_cast<const char*>(Wh)
                        + (size_t)half * 128 * DIM * sizeof(_Float16);
        #pragma unroll
        for (int s = 0; s < 8; ++s) {
            const int c  = s * 512 + threadIdx.x;   // 0..4095
            const int j  = c >> 5;                  // 0..127 (col within half)
            const int ko = (c & 31) << 4;           // 0..496 step 16 (bytes)
            *reinterpret_cast<h16x8*>(blb + j * 512 + (ko ^ ((j & 7) << 4))) =
                *reinterpret_cast<const h16x8*>(src + j * 512 + ko);
        }
        __syncthreads();

        // ---- MFMA: 8 col-tiles x 8 k-steps from LDS ----
        #pragma unroll
        for (int jt = 0; jt < 8; ++jt) {
            const int j = jt * 16 + r16;            // col within half
            const int jsw = (j & 7) << 4;
            #pragma unroll
            for (int ks = 0; ks < 8; ++ks) {
                const int ko = ks * 64 + kgrp * 16;
                const h16x8 bf = *reinterpret_cast<const h16x8*>(
                    blb + j * 512 + (ko ^ jsw));
                acc[half * 8 + jt] = __builtin_amdgcn_mfma_f32_16x16x32_f16(
                    af[ks], bf, acc[half * 8 + jt], 0, 0, 0);
            }
        }
    }

    // ---- epilogue: bias + fp16 store ----
    if (act) {
        #pragma unroll
        for (int h = 0; h < 2; ++h) {
            #pragma unroll
            for (int jt = 0; jt < 8; ++jt) {
                const int col = h * 128 + jt * 16 + r16;
                const float bv = bias[col];
                #pragma unroll
                for (int r = 0; r < 4; ++r) {
                    const int grow = m0 + kgrp * 4 + r;
                    if (grow < n)
                        hidden[(size_t)grow * DIM + col] =
                            (_Float16)(acc[h * 8 + jt][r] + bv);
                }
            }
        }
    }
}

// ---------------------------------------------------------------------------
// CSR build: histogram -> exclusive scan (2-level) -> bucket fill
// ---------------------------------------------------------------------------
__global__ __launch_bounds__(256) void histo(
    const int* __restrict__ rows, int* __restrict__ deg, int n_edges)
{
    int e = blockIdx.x * 256 + threadIdx.x;
    const int stride = gridDim.x * 256;
    for (; e < n_edges; e += stride)
        atomicAdd(&deg[rows[e]], 1);
}

__global__ __launch_bounds__(256) void scan_block(
    const int* __restrict__ deg, int* __restrict__ offs,
    int* __restrict__ bsums, int n)
{
    __shared__ int s[256];
    const int gid = blockIdx.x * 256 + threadIdx.x;
    const int v = (gid < n) ? deg[gid] : 0;
    s[threadIdx.x] = v;
    __syncthreads();
    #pragma unroll
    for (int d = 1; d < 256; d <<= 1) {
        const int t = (threadIdx.x >= d) ? s[threadIdx.x - d] : 0;
        __syncthreads();
        s[threadIdx.x] += t;
        __syncthreads();
    }
    if (gid < n) offs[gid] = s[threadIdx.x] - v;     // exclusive within block
    if (threadIdx.x == 255) bsums[blockIdx.x] = s[255];
}

__global__ __launch_bounds__(256) void scan_sums(int* __restrict__ bsums, int nb)
{
    __shared__ int s[256];
    const int v = (threadIdx.x < nb) ? bsums[threadIdx.x] : 0;
    s[threadIdx.x] = v;
    __syncthreads();
    #pragma unroll
    for (int d = 1; d < 256; d <<= 1) {
        const int t = (threadIdx.x >= d) ? s[threadIdx.x - d] : 0;
        __syncthreads();
        s[threadIdx.x] += t;
        __syncthreads();
    }
    if (threadIdx.x < nb) bsums[threadIdx.x] = s[threadIdx.x] - v;  // exclusive
}

__global__ __launch_bounds__(256) void scan_add(
    int* __restrict__ offs, const int* __restrict__ bsums, int n, int n_edges)
{
    const int gid = blockIdx.x * 256 + threadIdx.x;
    if (gid < n) offs[gid] += bsums[blockIdx.x];
    if (gid == n - 1) offs[n] = n_edges;
}

__global__ __launch_bounds__(256) void bucket_fill(
    const int* __restrict__ rows, const int* __restrict__ cols,
    const float* __restrict__ vals, const int* __restrict__ offs,
    int* __restrict__ deg, int2* __restrict__ eb, int n_edges)
{
    int e = blockIdx.x * 256 + threadIdx.x;
    const int stride = gridDim.x * 256;
    for (; e < n_edges; e += stride) {
        const int r = rows[e];
        const int old = atomicSub(&deg[r], 1);
        const int pos = offs[r] + old - 1;
        eb[pos] = make_int2(cols[e], __float_as_int(vals[e]));
    }
}

// ---------------------------------------------------------------------------
// Aggregation (gather, no atomics) + fused epilogue.
// One 64-lane wave per node; lane holds 4 of 256 features (fp16 gather, 8B).
// Unrolled x4, two accumulator chains. Streaming traffic (eb, x1, x2, y1,
// y2) is non-temporal so L2/L3 retain hidden (reused ~16x).
// y1 = relu(sum_e val*hidden[col]) + x1 ; y2 = x2.
// ---------------------------------------------------------------------------
__global__ __launch_bounds__(256) void aggregate(
    const _Float16* __restrict__ hidden, const int* __restrict__ offs,
    const int2* __restrict__ eb,
    const float* __restrict__ x1, const float* __restrict__ x2,
    float* __restrict__ y2, float* __restrict__ y1, int n)
{
    const int lane = threadIdx.x & 63;
    const int node = blockIdx.x * 4 + (threadIdx.x >> 6);
    if (node >= n) return;

    const int s = offs[node];
    const int e = offs[node + 1];
    const size_t fofs = (size_t)(lane * 4);

    float4 acc0 = make_float4(0.f, 0.f, 0.f, 0.f);
    float4 acc1 = make_float4(0.f, 0.f, 0.f, 0.f);

    int i = s;
    for (; i + 3 < e; i += 4) {
        const i32x2 p0 = __builtin_nontemporal_load(
            reinterpret_cast<const i32x2*>(&eb[i + 0]));
        const i32x2 p1 = __builtin_nontemporal_load(
            reinterpret_cast<const i32x2*>(&eb[i + 1]));
        const i32x2 p2 = __builtin_nontemporal_load(
            reinterpret_cast<const i32x2*>(&eb[i + 2]));
        const i32x2 p3 = __builtin_nontemporal_load(
            reinterpret_cast<const i32x2*>(&eb[i + 3]));
        const float4 h0 = ld_h4(hidden + (size_t)p0[0] * DIM + fofs);
        const float4 h1 = ld_h4(hidden + (size_t)p1[0] * DIM + fofs);
        const float4 h2 = ld_h4(hidden + (size_t)p2[0] * DIM + fofs);
        const float4 h3 = ld_h4(hidden + (size_t)p3[0] * DIM + fofs);
        const float v0 = __int_as_float(p0[1]);
        const float v1 = __int_as_float(p1[1]);
        const float v2 = __int_as_float(p2[1]);
        const float v3 = __int_as_float(p3[1]);
        acc0.x += v0 * h0.x + v1 * h1.x;
        acc0.y += v0 * h0.y + v1 * h1.y;
        acc0.z += v0 * h0.z + v1 * h1.z;
        acc0.w += v0 * h0.w + v1 * h1.w;
        acc1.x += v2 * h2.x + v3 * h3.x;
        acc1.y += v2 * h2.y + v3 * h3.y;
        acc1.z += v2 * h2.z + v3 * h3.z;
        acc1.w += v2 * h2.w + v3 * h3.w;
    }
    for (; i < e; ++i) {
        const i32x2 p0 = __builtin_nontemporal_load(
            reinterpret_cast<const i32x2*>(&eb[i]));
        const float v0 = __int_as_float(p0[1]);
        const float4 h0 = ld_h4(hidden + (size_t)p0[0] * DIM + fofs);
        acc0.x += v0 * h0.x;
        acc0.y += v0 * h0.y;
        acc0.z += v0 * h0.z;
        acc0.w += v0 * h0.w;
    }
    acc0.x += acc1.x; acc0.y += acc1.y; acc0.z += acc1.z; acc0.w += acc1.w;

    const size_t base = (size_t)node * DIM + fofs;
    const f32x4 a  = __builtin_nontemporal_load(
        reinterpret_cast<const f32x4*>(x1 + base));
    const f32x4 xx = __builtin_nontemporal_load(
        reinterpret_cast<const f32x4*>(x2 + base));
    f32x4 o;
    o[0] = fmaxf(acc0.x, 0.f) + a[0];
    o[1] = fmaxf(acc0.y, 0.f) + a[1];
    o[2] = fmaxf(acc0.z, 0.f) + a[2];
    o[3] = fmaxf(acc0.w, 0.f) + a[3];
    __builtin_nontemporal_store(o,  reinterpret_cast<f32x4*>(y1 + base));
    __builtin_nontemporal_store(xx, reinterpret_cast<f32x4*>(y2 + base));
}

// ---------------------------------------------------------------------------
// Fallback path (atomic scatter) if ws_size is too small for CSR build.
// ---------------------------------------------------------------------------
__global__ __launch_bounds__(256) void edge_scatter(
    const _Float16* __restrict__ hidden,
    const int* __restrict__ rows, const int* __restrict__ cols,
    const float* __restrict__ vals,
    float* __restrict__ support, int n_edges)
{
    const int lane = threadIdx.x & 63;
    const int wslot = (blockIdx.x << 2) | (threadIdx.x >> 6);
    const int n_slots = gridDim.x << 2;
    for (int e = wslot; e < n_edges; e += n_slots) {
        const int r = rows[e];
        const int c = cols[e];
        const float v = vals[e];
        const float4 h = ld_h4(hidden + (size_t)c * DIM + lane * 4);
        float* sp = support + (size_t)r * DIM + lane * 4;
        atomicAdd(sp + 0, v * h.x);
        atomicAdd(sp + 1, v * h.y);
        atomicAdd(sp + 2, v * h.z);
        atomicAdd(sp + 3, v * h.w);
    }
}

__global__ __launch_bounds__(256) void epilogue(
    const float* __restrict__ x1, const float* __restrict__ x2,
    float* __restrict__ out_y2, float* __restrict__ out_y1, size_t total4)
{
    const float4* x1v = reinterpret_cast<const float4*>(x1);
    const float4* x2v = reinterpret_cast<const float4*>(x2);
    float4* y2v = reinterpret_cast<float4*>(out_y2);
    float4* y1v = reinterpret_cast<float4*>(out_y1);
    size_t i = (size_t)blockIdx.x * blockDim.x + threadIdx.x;
    const size_t stride = (size_t)gridDim.x * blockDim.x;
    for (; i < total4; i += stride) {
        y2v[i] = x2v[i];
        float4 s = y1v[i];
        float4 a = x1v[i];
        float4 o;
        o.x = fmaxf(s.x, 0.f) + a.x;
        o.y = fmaxf(s.y, 0.f) + a.y;
        o.z = fmaxf(s.z, 0.f) + a.z;
        o.w = fmaxf(s.w, 0.f) + a.w;
        y1v[i] = o;
    }
}

extern "C" void kernel_launch(void* const* d_in, const int* in_sizes, int n_in,
                              void* d_out, int out_size, void* d_ws, size_t ws_size,
                              hipStream_t stream) {
    const float* x1   = (const float*)d_in[0];
    const float* x2   = (const float*)d_in[1];
    const int*   rows = (const int*)d_in[2];
    const int*   cols = (const int*)d_in[3];
    const float* vals = (const float*)d_in[4];
    const float* W    = (const float*)d_in[5];
    const float* bias = (const float*)d_in[6];

    const int n_nodes = in_sizes[0] / DIM;
    const int n_edges = in_sizes[2];
    const int nb = (n_nodes + 255) / 256;   // scan blocks (<=256 required)

    float* out     = (float*)d_out;
    float* out_y2  = out;                              // y2 = x2
    float* out_y1  = out + (size_t)n_nodes * DIM;      // y1

    // workspace layout (hidden fp16, Wh fp16)
    char* ws = (char*)d_ws;
    _Float16* hidden = (_Float16*)ws;
    size_t off = (size_t)n_nodes * DIM * sizeof(_Float16);
    _Float16* Wh = (_Float16*)(ws + off); off += (size_t)DIM * DIM * sizeof(_Float16);
    int* offs  = (int*)(ws + off);  off += (size_t)(n_nodes + 1) * sizeof(int);
    int* deg   = (int*)(ws + off);  off += (size_t)n_nodes * sizeof(int);
    int* bsums = (int*)(ws + off);  off += 256 * sizeof(int);
    off = (off + 15) & ~(size_t)15;
    int2* eb   = (int2*)(ws + off); off += (size_t)n_edges * sizeof(int2);
    const bool csr_ok = (off <= ws_size) && (nb <= 256);

    // 1) Wh = fp16(W); hidden = x2 @ W^T + b  (LDS-staged MFMA, fp32 accum)
    cvt_w<<<DIM * DIM / 256, 256, 0, stream>>>(W, Wh);
    const int n_tiles = (n_nodes + 15) / 16;
    gemm_mfma<<<(n_tiles + 7) / 8, 512, 0, stream>>>(
        x2, Wh, bias, hidden, n_nodes, n_tiles);

    if (csr_ok) {
        // 2) CSR build
        (void)hipMemsetAsync(deg, 0, (size_t)n_nodes * sizeof(int), stream);
        histo<<<(n_edges + 255) / 256, 256, 0, stream>>>(rows, deg, n_edges);
        scan_block<<<nb, 256, 0, stream>>>(deg, offs, bsums, n_nodes);
        scan_sums<<<1, 256, 0, stream>>>(bsums, nb);
        scan_add<<<nb, 256, 0, stream>>>(offs, bsums, n_nodes, n_edges);
        bucket_fill<<<(n_edges + 255) / 256, 256, 0, stream>>>(
            rows, cols, vals, offs, deg, eb, n_edges);

        // 3) gather-aggregate + fused epilogue
        aggregate<<<(n_nodes + 3) / 4, 256, 0, stream>>>(
            hidden, offs, eb, x1, x2, out_y2, out_y1, n_nodes);
    } else {
        // fallback: atomic scatter into out_y1 (used as support accumulator)
        (void)hipMemsetAsync(out_y1, 0, (size_t)n_nodes * DIM * sizeof(float), stream);
        edge_scatter<<<2048, 256, 0, stream>>>(hidden, rows, cols, vals,
                                               out_y1, n_edges);
        const size_t total4 = (size_t)n_nodes * DIM / 4;
        epilogue<<<2048, 256, 0, stream>>>(x1, x2, out_y2, out_y1, total4);
    }
}